// Round 15
// baseline (252.863 us; speedup 1.0000x reference)
//
#include <hip/hip_runtime.h>
#include <hip/hip_bf16.h>
#include <stdint.h>

#define BB 4
#define TT 2048
#define CC 1024
#define HH 8
#define DD 128

typedef unsigned short u16;
typedef unsigned int u32;
typedef unsigned long long u64;
typedef __attribute__((ext_vector_type(4))) float f32x4;
typedef __attribute__((ext_vector_type(16))) float f32x16;
typedef __attribute__((ext_vector_type(8))) __bf16 bf16x8;

#define SL2C (0.08838834764831845f * 1.442695040888963f)   // 1/sqrt(128) * log2(e), folded into Q
#define L2E  1.442695040888963f

__device__ __forceinline__ float bf2f(u16 u){ u32 x=((u32)u)<<16; float f; __builtin_memcpy(&f,&x,4); return f; }
__device__ __forceinline__ u16 f2bf(float f){ u32 x; __builtin_memcpy(&x,&f,4); x += 0x7fffu + ((x>>16)&1u); return (u16)(x>>16); }

__device__ __forceinline__ void gload16(const void* g, void* l){
  __builtin_amdgcn_global_load_lds((const __attribute__((address_space(1))) u32*)g,
                                   (__attribute__((address_space(3))) u32*)l, 16, 0, 0);
}
__device__ __forceinline__ f32x4 mfma16(bf16x8 a, bf16x8 b, f32x4 c){
  return __builtin_amdgcn_mfma_f32_16x16x32_bf16(a,b,c,0,0,0);
}
__device__ __forceinline__ f32x16 mfma32(bf16x8 a, bf16x8 b, f32x16 c){
  return __builtin_amdgcn_mfma_f32_32x32x16_bf16(a,b,c,0,0,0);
}
__device__ __forceinline__ u32 cvtpk(float lo, float hi){
  u32 r; asm("v_cvt_pk_bf16_f32 %0, %1, %2" : "=v"(r) : "v"(lo), "v"(hi)); return r;
}
__device__ __forceinline__ void pl32swap(u32& d, u32& s){
  asm volatile("v_permlane32_swap_b32 %0, %1" : "+v"(d), "+v"(s));
}
union FRAG { u32 u[4]; bf16x8 v; };

// ---------------- LayerNorm: f32 x -> bf16 xn ----------------
__global__ void ln_k(const float* __restrict__ x, const float* __restrict__ g,
                     const float* __restrict__ bta, u16* __restrict__ xn){
  int row = blockIdx.x, tid = threadIdx.x;
  const float4 v = ((const float4*)(x + (size_t)row*CC))[tid];
  float s = v.x+v.y+v.z+v.w;
  float ss = v.x*v.x+v.y*v.y+v.z*v.z+v.w*v.w;
  #pragma unroll
  for(int m=1;m<64;m<<=1){ s += __shfl_xor(s,m); ss += __shfl_xor(ss,m); }
  __shared__ float red[8];
  if((tid&63)==0){ red[tid>>6]=s; red[4+(tid>>6)]=ss; }
  __syncthreads();
  float ts = red[0]+red[1]+red[2]+red[3];
  float tss = red[4]+red[5]+red[6]+red[7];
  float mu = ts*(1.0f/CC);
  float rs = rsqrtf(tss*(1.0f/CC) - mu*mu + 1e-5f);
  int c0 = tid*4;
  ushort4 o;
  o.x = f2bf((v.x-mu)*rs*g[c0+0]+bta[c0+0]);
  o.y = f2bf((v.y-mu)*rs*g[c0+1]+bta[c0+1]);
  o.z = f2bf((v.z-mu)*rs*g[c0+2]+bta[c0+2]);
  o.w = f2bf((v.w-mu)*rs*g[c0+3]+bta[c0+3]);
  ((ushort4*)(xn + (size_t)row*CC))[tid] = o;
}

// ---------------- prep: weights f32->bf16 + RoPE tables ----------------
__global__ void prep_k(const float* __restrict__ wq, const float* __restrict__ wk,
                       const float* __restrict__ wv, const float* __restrict__ wo,
                       u16* __restrict__ out, float* __restrict__ cosT, float* __restrict__ sinT){
  if(blockIdx.x < 4096){
    int i = blockIdx.x*256 + threadIdx.x;
    int sel = i>>18;
    const float* src = sel==0?wq: sel==1?wk: sel==2?wv:wo;
    float4 v = ((const float4*)src)[i & 262143];
    ushort4 o; o.x=f2bf(v.x); o.y=f2bf(v.y); o.z=f2bf(v.z); o.w=f2bf(v.w);
    ((ushort4*)out)[i] = o;
  } else {
    int i = (blockIdx.x-4096)*256 + threadIdx.x;
    int t = i>>6, j = i&63;
    float inv = powf(10000.0f, -(float)(2*j)*(1.0f/128.0f));
    float a = (float)t * inv;
    cosT[i] = cosf(a);
    sinT[i] = sinf(a);
  }
}

// ---------------- qp/kp from ROPED Q (prescaled) and ROPED KF ----------------
__global__ void qpkp_k(const u16* __restrict__ Qb, const u16* __restrict__ KF,
                       const float* __restrict__ dirs, float* __restrict__ qp, float* __restrict__ kp){
  const float INV_SL2 = 1.0f/SL2C;
  int idx = blockIdx.x*256 + threadIdx.x;   // (b*H+h)*T + t
  int b = idx>>14, rem = idx & 16383;
  int h = rem>>11, t = rem & 2047;
  int bh = b*HH + h;
  float d0 = dirs[h*3], d1 = dirs[h*3+1], d2 = dirs[h*3+2];
  size_t qbase = ((size_t)(b*TT + t))*CC + h*DD;
  qp[idx] = (bf2f(Qb[qbase])*d0 + bf2f(Qb[qbase+1])*d1 + bf2f(Qb[qbase+2])*d2) * INV_SL2;
  size_t kb = ((size_t)(bh*64 + (t>>5))*8)*512 + (size_t)(t&31)*8;
  kp[idx] = bf2f(KF[kb])*d0 + bf2f(KF[kb+1])*d1 + bf2f(KF[kb+2])*d2;
}

// ---------------- GEMM (R14-proven) ----------------
// MODE 0: Q rope+prescale -> Qb. MODE 5: K rope -> KF frags. MODE 4: V -> VF frags. MODE 2: f32 + resid.
template<int MODE>
__global__ __launch_bounds__(256) void gemm_k(const u16* __restrict__ A, const u16* __restrict__ W,
                                              u16* __restrict__ outb, float* __restrict__ outf,
                                              const float* __restrict__ resid,
                                              const float* __restrict__ cosT, const float* __restrict__ sinT){
  __shared__ __align__(16) u16 sbuf[16384];
  u16* As = sbuf;
  u16* Bs = sbuf + 8192;
  const int K = CC;
  int m0 = blockIdx.x*128, n0 = blockIdx.y*128;
  int tid = threadIdx.x, w = tid>>6, l = tid&63;
  int li = l&15, lg = l>>4;
  int wm = w>>1, wn = w&1;
  f32x4 acc[4][4] = {};
  for(int k0=0; k0<K; k0+=64){
    #pragma unroll
    for(int i=0;i<4;i++){
      int L = (w*4+i)*1024 + l*16;
      int row = L>>7;
      int colb = (L&127) ^ ((row&7)<<4);
      gload16(A + ((size_t)(m0+row)*K + k0 + (colb>>1)), (char*)As + (w*4+i)*1024);
      gload16(W + ((size_t)(n0+row)*K + k0 + (colb>>1)), (char*)Bs + (w*4+i)*1024);
    }
    __syncthreads();
    #pragma unroll
    for(int kc=0;kc<2;kc++){
      bf16x8 af[4], bfr[4];
      #pragma unroll
      for(int mi=0;mi<4;mi++){
        int row = wm*64 + mi*16 + li;
        int colb = (kc*64 + lg*16) ^ ((row&7)<<4);
        af[mi] = *(const bf16x8*)((const char*)As + row*128 + colb);
      }
      #pragma unroll
      for(int ni=0;ni<4;ni++){
        int row = wn*64 + ni*16 + li;
        int colb = (kc*64 + lg*16) ^ ((row&7)<<4);
        bfr[ni] = *(const bf16x8*)((const char*)Bs + row*128 + colb);
      }
      #pragma unroll
      for(int mi=0;mi<4;mi++){
        #pragma unroll
        for(int ni=0;ni<4;ni++)
          acc[mi][ni] = mfma16(af[mi], bfr[ni], acc[mi][ni]);
      }
    }
    __syncthreads();
  }

  if(MODE==0 || MODE==5){
    #pragma unroll
    for(int mi=0;mi<4;mi++){
      #pragma unroll
      for(int ni=0;ni<4;ni++){
        int c = wn*64 + ni*16 + li;
        #pragma unroll
        for(int r=0;r<4;r++){
          int rr = wm*64 + mi*16 + lg*4 + r;
          sbuf[rr*128 + (c ^ ((rr&15)<<3))] = f2bf(acc[mi][ni][r]);
        }
      }
    }
    __syncthreads();
    int rowl = tid & 127, half = tid >> 7;
    int grow = m0 + rowl;
    int t = grow & (TT-1);
    int swz = (rowl&15)<<3;
    const float* cbase = cosT + t*64;
    const float* sbase = sinT + t*64;
    #pragma unroll
    for(int g=0; g<16; g++){
      int c0 = half*64 + g*4;
      int j0 = c0 & 63;
      float4 cv = *(const float4*)(cbase + j0);
      float4 sv4 = *(const float4*)(sbase + j0);
      ushort4 se4 = *(const ushort4*)&sbuf[rowl*128 + (c0 ^ swz)];
      ushort4 pa4 = *(const ushort4*)&sbuf[rowl*128 + ((c0^64) ^ swz)];
      float se[4] = {bf2f(se4.x),bf2f(se4.y),bf2f(se4.z),bf2f(se4.w)};
      float pa[4] = {bf2f(pa4.x),bf2f(pa4.y),bf2f(pa4.z),bf2f(pa4.w)};
      float cc4[4] = {cv.x,cv.y,cv.z,cv.w};
      float ss4[4] = {sv4.x,sv4.y,sv4.z,sv4.w};
      ushort4 o; u16* op = (u16*)&o;
      #pragma unroll
      for(int e=0;e<4;e++){
        float v = half ? (se[e]*cc4[e] + pa[e]*ss4[e]) : (se[e]*cc4[e] - pa[e]*ss4[e]);
        if(MODE==0) v *= SL2C;
        op[e] = f2bf(v);
      }
      if(MODE==0){
        *(ushort4*)(outb + (size_t)grow*CC + n0 + c0) = o;
      } else {
        int b = grow>>11;
        int h = n0>>7;
        int bh = b*HH + h;
        int d0 = c0;
        size_t of = (((size_t)(bh*64 + (t>>5))*8) + (d0>>4))*512 + (((d0>>3)&1)*32 + (t&31))*8 + (d0&7);
        *(ushort4*)(outb + of) = o;
      }
    }
    return;
  }

  #pragma unroll
  for(int mi=0;mi<4;mi++){
    #pragma unroll
    for(int ni=0;ni<4;ni++){
      if(MODE==4){
        int row0 = m0 + wm*64 + mi*16 + lg*4;
        int col = n0 + wn*64 + ni*16 + li;
        int t = row0 & 2047, b = row0>>11;
        int h = col>>7, d = col&127;
        int bh = b*HH + h;
        size_t o = (((size_t)(bh*64 + (t>>5))*8) + (d>>5)*2 + ((t>>4)&1))*512
                   + (((t>>3)&1)*32 + (d&31))*8 + (t&7);
        ushort4 pk;
        pk.x = f2bf(acc[mi][ni][0]); pk.y = f2bf(acc[mi][ni][1]);
        pk.z = f2bf(acc[mi][ni][2]); pk.w = f2bf(acc[mi][ni][3]);
        *(ushort4*)(outb + o) = pk;
      } else {
        #pragma unroll
        for(int r=0;r<4;r++){
          int row = m0 + wm*64 + mi*16 + lg*4 + r;
          int col = n0 + wn*64 + ni*16 + li;
          size_t o = (size_t)row*CC + col;
          outf[o] = acc[mi][ni][r] + resid[o];
        }
      }
    }
  }
}

// ================= GEO attention (rank-1 logits; no K frags, no QK MFMA) =================
struct GeoState { float m2, l2; f32x16 a2[4]; };

__device__ __forceinline__ void run_geo(int t, int klo, int khi, int bh,
                                        int l5, int q31,
                                        const u16* __restrict__ VF, const float* __restrict__ qp,
                                        const float* __restrict__ kp, GeoState& S){
  const f32x16 zf = {};
  S.m2 = -__builtin_inff(); S.l2 = 0.f;
  #pragma unroll
  for(int dt=0;dt<4;dt++) S.a2[dt] = zf;
  if(khi <= klo) return;

  int q0 = t*32, q = q0 + q31;
  float qpl = qp[(size_t)bh*TT + q] * L2E;
  const u16* vfp = VF + (size_t)bh*64*4096 + (size_t)klo*4096 + (size_t)(q31 + 32*l5)*8;
  const float* kpb = kp + (size_t)bh*TT + l5*8;

  for(int is=klo; is<khi; ++is){
    int ksub = is*32;
    // logits in B-operand layout: elem (kb2, j) -> k = ksub + kb2*16 + l5*8 + j
    float lg[16];
    #pragma unroll
    for(int kb2=0;kb2<2;kb2++){
      float4 ka = *(const float4*)(kpb + ksub + kb2*16);
      float4 kb4 = *(const float4*)(kpb + ksub + kb2*16 + 4);
      lg[kb2*8+0]=qpl*ka.x;  lg[kb2*8+1]=qpl*ka.y;  lg[kb2*8+2]=qpl*ka.z;  lg[kb2*8+3]=qpl*ka.w;
      lg[kb2*8+4]=qpl*kb4.x; lg[kb2*8+5]=qpl*kb4.y; lg[kb2*8+6]=qpl*kb4.z; lg[kb2*8+7]=qpl*kb4.w;
    }
    if(ksub + 31 > q0){
      #pragma unroll
      for(int e=0;e<16;e++){
        int kg = ksub + (e>>3)*16 + l5*8 + (e&7);
        if(kg > q) lg[e] = -__builtin_inff();
      }
    }
    float gx = -__builtin_inff();
    #pragma unroll
    for(int e=0;e<16;e++) gx = fmaxf(gx, lg[e]);
    gx = fmaxf(gx, __shfl_xor(gx,32));
    if(__ballot(gx > S.m2+8.f)){
      float mn2 = fmaxf(S.m2,gx);
      float c2 = exp2f(S.m2-mn2);
      S.l2 *= c2; S.m2 = mn2;
      #pragma unroll
      for(int dt=0;dt<4;dt++) S.a2[dt] *= c2;
    }
    float rs2 = 0.f;
    #pragma unroll
    for(int e=0;e<16;e++){ lg[e] = exp2f(lg[e] - S.m2); rs2 += lg[e]; }
    rs2 += __shfl_xor(rs2,32);
    S.l2 += rs2;

    #pragma unroll
    for(int kb2=0;kb2<2;kb2++){
      FRAG f2;
      #pragma unroll
      for(int j2=0;j2<4;j2++) f2.u[j2] = cvtpk(lg[kb2*8+2*j2], lg[kb2*8+2*j2+1]);
      bf16x8 pb2 = f2.v;
      bf16x8 vf0 = *(const bf16x8*)(vfp + (0+kb2)*512);
      bf16x8 vf1 = *(const bf16x8*)(vfp + (2+kb2)*512);
      bf16x8 vf2 = *(const bf16x8*)(vfp + (4+kb2)*512);
      bf16x8 vf3 = *(const bf16x8*)(vfp + (6+kb2)*512);
      __builtin_amdgcn_s_setprio(1);
      S.a2[0] = mfma32(vf0, pb2, S.a2[0]);
      S.a2[1] = mfma32(vf1, pb2, S.a2[1]);
      S.a2[2] = mfma32(vf2, pb2, S.a2[2]);
      S.a2[3] = mfma32(vf3, pb2, S.a2[3]);
      __builtin_amdgcn_s_setprio(0);
    }
    vfp += 4096;
  }
}

// geo kernel: pair-balanced, LDS merge; writes NORMALIZED o2 (bf16) to G
__global__ __launch_bounds__(128,3) void attn_geo(const u16* __restrict__ VF, const float* __restrict__ qp,
                                                  const float* __restrict__ kp, u16* __restrict__ G){
  __shared__ __align__(16) float lp2[4*64*16];
  __shared__ float lml[32*2];
  int bid = blockIdx.x;
  int xcd = bid&7, r = bid>>3;
  int bh = xcd*4 + (r&3);
  int p = r>>2;
  int b = bh>>3, h = bh&7;
  int tid = threadIdx.x, w = tid>>6, l = tid&63;
  int l5 = l>>5, q31 = l&31;

  GeoState S;
  if(w==0){
    run_geo(p, 0, p+1, bh, l5, q31, VF, qp, kp, S);
    {
      float rl2 = 1.0f/S.l2;
      int q = p*32 + q31;
      u16* gb = G + (size_t)(b*TT + q)*CC + h*DD;
      #pragma unroll
      for(int dt=0;dt<4;dt++){
        #pragma unroll
        for(int m=0;m<8;m++){
          int d = dt*32 + (2*m&3) + 8*(m>>1) + 4*l5;
          *(u32*)(gb + d) = cvtpk(S.a2[dt][2*m]*rl2, S.a2[dt][2*m+1]*rl2);
        }
      }
    }
    run_geo(63-p, 0, 31-p, bh, l5, q31, VF, qp, kp, S);
    #pragma unroll
    for(int dt=0;dt<4;dt++) *(f32x16*)&lp2[(dt*64 + l)*16] = S.a2[dt];
    if(l5==0){ lml[q31*2+0] = S.m2; lml[q31*2+1] = S.l2; }
    __syncthreads();
  } else {
    run_geo(63-p, 31-p, 64-p, bh, l5, q31, VF, qp, kp, S);
    __syncthreads();
    float mA = lml[q31*2+0], lA = lml[q31*2+1];
    float M = fmaxf(mA, S.m2);
    float wA = exp2f(mA-M), wB = exp2f(S.m2-M);
    float r2 = 1.0f/(wA*lA + wB*S.l2);
    int q = (63-p)*32 + q31;
    u16* gb = G + (size_t)(b*TT + q)*CC + h*DD;
    #pragma unroll
    for(int dt=0;dt<4;dt++){
      f32x16 pa = *(const f32x16*)&lp2[(dt*64 + l)*16];
      #pragma unroll
      for(int m=0;m<8;m++){
        int d = dt*32 + (2*m&3) + 8*(m>>1) + 4*l5;
        float oa = (wA*pa[2*m]   + wB*S.a2[dt][2*m])*r2;
        float ob = (wA*pa[2*m+1] + wB*S.a2[dt][2*m+1])*r2;
        *(u32*)(gb + d) = cvtpk(oa, ob);
      }
    }
  }
}

// ================= REGULAR attention (single accumulator; 3 waves/SIMD target) =================
struct RegState { float m1, l1; f32x16 a1[4]; };

__device__ __forceinline__ void run_reg(int t, int klo, int khi, int bh, int b, int h,
                                        int l5, int q31,
                                        const u16* __restrict__ Q, const u16* __restrict__ KF,
                                        const u16* __restrict__ VF, RegState& S){
  const f32x16 zf = {};
  S.m1 = -__builtin_inff(); S.l1 = 0.f;
  #pragma unroll
  for(int dt=0;dt<4;dt++) S.a1[dt] = zf;
  if(khi <= klo) return;

  int q0 = t*32, q = q0 + q31;
  bf16x8 qf[8];
  {
    const u16* qbase = Q + ((size_t)(b*TT + q)*CC + h*DD);
    #pragma unroll
    for(int db=0;db<8;db++) qf[db] = *(const bf16x8*)(qbase + db*16 + l5*8);
  }
  const u16* kfp = KF + (size_t)bh*64*4096 + (size_t)klo*4096 + (size_t)(q31 + 32*l5)*8;
  const u16* vfp = VF + (size_t)bh*64*4096 + (size_t)klo*4096 + (size_t)(q31 + 32*l5)*8;

  for(int is=klo; is<khi; ++is){
    int ksub = is*32;

    // QK^T in two halves (4 kf regs live at a time -> lower VGPR pressure)
    f32x16 s0 = {}, s1a = {};
    {
      bf16x8 k0 = *(const bf16x8*)(kfp + 0*512);
      bf16x8 k1 = *(const bf16x8*)(kfp + 1*512);
      bf16x8 k2 = *(const bf16x8*)(kfp + 2*512);
      bf16x8 k3 = *(const bf16x8*)(kfp + 3*512);
      __builtin_amdgcn_s_setprio(1);
      s0  = mfma32(k0, qf[0], s0);  s1a = mfma32(k1, qf[1], s1a);
      s0  = mfma32(k2, qf[2], s0);  s1a = mfma32(k3, qf[3], s1a);
      __builtin_amdgcn_s_setprio(0);
      k0 = *(const bf16x8*)(kfp + 4*512);
      k1 = *(const bf16x8*)(kfp + 5*512);
      k2 = *(const bf16x8*)(kfp + 6*512);
      k3 = *(const bf16x8*)(kfp + 7*512);
      __builtin_amdgcn_s_setprio(1);
      s0  = mfma32(k0, qf[4], s0);  s1a = mfma32(k1, qf[5], s1a);
      s0  = mfma32(k2, qf[6], s0);  s1a = mfma32(k3, qf[7], s1a);
      __builtin_amdgcn_s_setprio(0);
    }

    float sv[16];
    #pragma unroll
    for(int rr=0;rr<16;rr++) sv[rr] = s0[rr]+s1a[rr];     // Q pre-scaled: log2 domain
    if(ksub + 31 > q0){
      #pragma unroll
      for(int rr=0;rr<16;rr++){
        int kg = ksub + (rr&3) + 8*(rr>>2) + 4*l5;
        if(kg > q) sv[rr] = -__builtin_inff();
      }
    }

    float mx=-__builtin_inff();
    #pragma unroll
    for(int rr=0;rr<16;rr++) mx = fmaxf(mx, sv[rr]);
    mx = fmaxf(mx, __shfl_xor(mx,32));
    if(__ballot(mx > S.m1+8.f)){
      float mn1 = fmaxf(S.m1,mx);
      float c1 = exp2f(S.m1-mn1);
      S.l1 *= c1; S.m1 = mn1;
      #pragma unroll
      for(int dt=0;dt<4;dt++) S.a1[dt] *= c1;
    }
    float rs1=0.f;
    #pragma unroll
    for(int rr=0;rr<16;rr++){ sv[rr] = exp2f(sv[rr] - S.m1); rs1 += sv[rr]; }
    rs1 += __shfl_xor(rs1,32);
    S.l1 += rs1;

    u32 P1[8];
    #pragma unroll
    for(int m=0;m<8;m++) P1[m] = cvtpk(sv[2*m], sv[2*m+1]);
    pl32swap(P1[0],P1[2]); pl32swap(P1[1],P1[3]); pl32swap(P1[4],P1[6]); pl32swap(P1[5],P1[7]);

    #pragma unroll
    for(int kb2=0;kb2<2;kb2++){
      FRAG f1;
      #pragma unroll
      for(int j2=0;j2<4;j2++) f1.u[j2] = P1[kb2*4+j2];
      bf16x8 pb1 = f1.v;
      bf16x8 vf0 = *(const bf16x8*)(vfp + (0+kb2)*512);
      bf16x8 vf1 = *(const bf16x8*)(vfp + (2+kb2)*512);
      bf16x8 vf2 = *(const bf16x8*)(vfp + (4+kb2)*512);
      bf16x8 vf3 = *(const bf16x8*)(vfp + (6+kb2)*512);
      __builtin_amdgcn_s_setprio(1);
      S.a1[0] = mfma32(vf0, pb1, S.a1[0]);
      S.a1[1] = mfma32(vf1, pb1, S.a1[1]);
      S.a1[2] = mfma32(vf2, pb1, S.a1[2]);
      S.a1[3] = mfma32(vf3, pb1, S.a1[3]);
      __builtin_amdgcn_s_setprio(0);
    }
    kfp += 4096; vfp += 4096;
  }
}

// regular kernel: pair-balanced, LDS merge; mixes with geo scratch G in epilogue
__global__ __launch_bounds__(128,3) void attn_reg(const u16* __restrict__ Q, const u16* __restrict__ KF,
                                                  const u16* __restrict__ VF, const u16* __restrict__ G,
                                                  const float* __restrict__ hs, u16* __restrict__ outp){
  __shared__ __align__(16) float lp1[4*64*16];
  __shared__ float lml[32*2];
  int bid = blockIdx.x;
  int xcd = bid&7, r = bid>>3;
  int bh = xcd*4 + (r&3);
  int p = r>>2;
  int b = bh>>3, h = bh&7;
  int tid = threadIdx.x, w = tid>>6, l = tid&63;
  int l5 = l>>5, q31 = l&31;
  float sh = hs[h];

  RegState S;
  if(w==0){
    run_reg(p, 0, p+1, bh, b, h, l5, q31, Q, KF, VF, S);
    {
      float rl1 = 1.0f/S.l1;
      int q = p*32 + q31;
      const u16* gb = G + (size_t)(b*TT + q)*CC + h*DD;
      u16* ob = outp + (size_t)(b*TT + q)*CC + h*DD;
      #pragma unroll
      for(int dt=0;dt<4;dt++){
        #pragma unroll
        for(int m=0;m<8;m++){
          int d = dt*32 + (2*m&3) + 8*(m>>1) + 4*l5;
          u32 gpk = *(const u32*)(gb + d);
          float g0 = bf2f((u16)gpk), g1 = bf2f((u16)(gpk>>16));
          float o0 = S.a1[dt][2*m]*rl1, o1v = S.a1[dt][2*m+1]*rl1;
          *(u32*)(ob + d) = cvtpk(o0 + sh*(g0-o0), o1v + sh*(g1-o1v));
        }
      }
    }
    run_reg(63-p, 0, 31-p, bh, b, h, l5, q31, Q, KF, VF, S);
    #pragma unroll
    for(int dt=0;dt<4;dt++) *(f32x16*)&lp1[(dt*64 + l)*16] = S.a1[dt];
    if(l5==0){ lml[q31*2+0] = S.m1; lml[q31*2+1] = S.l1; }
    __syncthreads();
  } else {
    run_reg(63-p, 31-p, 64-p, bh, b, h, l5, q31, Q, KF, VF, S);
    __syncthreads();
    float mA = lml[q31*2+0], lA = lml[q31*2+1];
    float M = fmaxf(mA, S.m1);
    float wA = exp2f(mA-M), wB = exp2f(S.m1-M);
    float r1 = 1.0f/(wA*lA + wB*S.l1);
    int q = (63-p)*32 + q31;
    const u16* gb = G + (size_t)(b*TT + q)*CC + h*DD;
    u16* ob = outp + (size_t)(b*TT + q)*CC + h*DD;
    #pragma unroll
    for(int dt=0;dt<4;dt++){
      f32x16 pa = *(const f32x16*)&lp1[(dt*64 + l)*16];
      #pragma unroll
      for(int m=0;m<8;m++){
        int d = dt*32 + (2*m&3) + 8*(m>>1) + 4*l5;
        float o0 = (wA*pa[2*m]   + wB*S.a1[dt][2*m])*r1;
        float o1v = (wA*pa[2*m+1] + wB*S.a1[dt][2*m+1])*r1;
        u32 gpk = *(const u32*)(gb + d);
        float g0 = bf2f((u16)gpk), g1 = bf2f((u16)(gpk>>16));
        *(u32*)(ob + d) = cvtpk(o0 + sh*(g0-o0), o1v + sh*(g1-o1v));
      }
    }
  }
}

extern "C" void kernel_launch(void* const* d_in, const int* in_sizes, int n_in,
                              void* d_out, int out_size, void* d_ws, size_t ws_size,
                              hipStream_t stream){
  (void)in_sizes; (void)n_in; (void)out_size; (void)ws_size;
  const float* x   = (const float*)d_in[0];
  const float* Wq  = (const float*)d_in[1];
  const float* Wk  = (const float*)d_in[2];
  const float* Wv  = (const float*)d_in[3];
  const float* Wo  = (const float*)d_in[4];
  const float* lng = (const float*)d_in[5];
  const float* lnb = (const float*)d_in[6];
  const float* hsc = (const float*)d_in[7];
  const float* hdr = (const float*)d_in[8];

  char* ws = (char*)d_ws;
  const size_t MB = 1048576;
  u16* xn   = (u16*)ws;                 // 16MB (LN out, later attn out)
  u16* wbf  = (u16*)(ws + 16*MB);       // 8MB bf16 weights Wq|Wk|Wv|Wo
  u16* Qb   = (u16*)(ws + 24*MB);       // 16MB roped+prescaled Q
  u16* G    = (u16*)(ws + 40*MB);       // 16MB geo output scratch (normalized o2)
  u16* VF   = (u16*)(ws + 56*MB);       // 16MB packed V fragments
  u16* KF   = (u16*)(ws + 72*MB);       // 16MB packed roped K fragments
  float* cosT = (float*)(ws + 88*MB);
  float* sinT = cosT + 131072;
  float* qp   = sinT + 131072;
  float* kp   = qp + 65536;

  ln_k<<<8192,256,0,stream>>>(x, lng, lnb, xn);
  prep_k<<<4608,256,0,stream>>>(Wq,Wk,Wv,Wo,wbf,cosT,sinT);
  gemm_k<0><<<dim3(64,8),256,0,stream>>>(xn, wbf,          Qb, nullptr, nullptr, cosT, sinT);
  gemm_k<5><<<dim3(64,8),256,0,stream>>>(xn, wbf+1048576,  KF, nullptr, nullptr, cosT, sinT);
  gemm_k<4><<<dim3(64,8),256,0,stream>>>(xn, wbf+2097152,  VF, nullptr, nullptr, nullptr, nullptr);
  qpkp_k<<<256,256,0,stream>>>(Qb,KF,hdr,qp,kp);
  attn_geo<<<1024,128,0,stream>>>(VF,qp,kp,G);
  attn_reg<<<1024,128,0,stream>>>(Qb,KF,VF,G,hsc,xn);
  gemm_k<2><<<dim3(64,8),256,0,stream>>>(xn, wbf+3145728, nullptr, (float*)d_out, x, nullptr, nullptr);
}

// Round 16
// 225.713 us; speedup vs baseline: 1.1203x; 1.1203x over previous
//
#include <hip/hip_runtime.h>
#include <hip/hip_bf16.h>
#include <stdint.h>

#define BB 4
#define TT 2048
#define CC 1024
#define HH 8
#define DD 128

typedef unsigned short u16;
typedef unsigned int u32;
typedef unsigned long long u64;
typedef __attribute__((ext_vector_type(4))) float f32x4;
typedef __attribute__((ext_vector_type(16))) float f32x16;
typedef __attribute__((ext_vector_type(8))) __bf16 bf16x8;

#define SL2C (0.08838834764831845f * 1.442695040888963f)   // 1/sqrt(128) * log2(e), folded into Q

__device__ __forceinline__ float bf2f(u16 u){ u32 x=((u32)u)<<16; float f; __builtin_memcpy(&f,&x,4); return f; }
__device__ __forceinline__ u16 f2bf(float f){ u32 x; __builtin_memcpy(&x,&f,4); x += 0x7fffu + ((x>>16)&1u); return (u16)(x>>16); }

__device__ __forceinline__ void gload16(const void* g, void* l){
  __builtin_amdgcn_global_load_lds((const __attribute__((address_space(1))) u32*)g,
                                   (__attribute__((address_space(3))) u32*)l, 16, 0, 0);
}
__device__ __forceinline__ f32x4 mfma16(bf16x8 a, bf16x8 b, f32x4 c){
  return __builtin_amdgcn_mfma_f32_16x16x32_bf16(a,b,c,0,0,0);
}
__device__ __forceinline__ f32x16 mfma32(bf16x8 a, bf16x8 b, f32x16 c){
  return __builtin_amdgcn_mfma_f32_32x32x16_bf16(a,b,c,0,0,0);
}
__device__ __forceinline__ u32 cvtpk(float lo, float hi){
  u32 r; asm("v_cvt_pk_bf16_f32 %0, %1, %2" : "=v"(r) : "v"(lo), "v"(hi)); return r;
}
__device__ __forceinline__ void pl32swap(u32& d, u32& s){
  asm volatile("v_permlane32_swap_b32 %0, %1" : "+v"(d), "+v"(s));
}
union FRAG { u32 u[4]; bf16x8 v; };

// ---------------- LayerNorm: f32 x -> bf16 xn ----------------
__global__ void ln_k(const float* __restrict__ x, const float* __restrict__ g,
                     const float* __restrict__ bta, u16* __restrict__ xn){
  int row = blockIdx.x, tid = threadIdx.x;
  const float4 v = ((const float4*)(x + (size_t)row*CC))[tid];
  float s = v.x+v.y+v.z+v.w;
  float ss = v.x*v.x+v.y*v.y+v.z*v.z+v.w*v.w;
  #pragma unroll
  for(int m=1;m<64;m<<=1){ s += __shfl_xor(s,m); ss += __shfl_xor(ss,m); }
  __shared__ float red[8];
  if((tid&63)==0){ red[tid>>6]=s; red[4+(tid>>6)]=ss; }
  __syncthreads();
  float ts = red[0]+red[1]+red[2]+red[3];
  float tss = red[4]+red[5]+red[6]+red[7];
  float mu = ts*(1.0f/CC);
  float rs = rsqrtf(tss*(1.0f/CC) - mu*mu + 1e-5f);
  int c0 = tid*4;
  ushort4 o;
  o.x = f2bf((v.x-mu)*rs*g[c0+0]+bta[c0+0]);
  o.y = f2bf((v.y-mu)*rs*g[c0+1]+bta[c0+1]);
  o.z = f2bf((v.z-mu)*rs*g[c0+2]+bta[c0+2]);
  o.w = f2bf((v.w-mu)*rs*g[c0+3]+bta[c0+3]);
  ((ushort4*)(xn + (size_t)row*CC))[tid] = o;
}

// ---------------- prep: weights f32->bf16 (blocks 0..4095) + RoPE tables (blocks 4096..4607) ----------------
__global__ void prep_k(const float* __restrict__ wq, const float* __restrict__ wk,
                       const float* __restrict__ wv, const float* __restrict__ wo,
                       u16* __restrict__ out, float* __restrict__ cosT, float* __restrict__ sinT){
  if(blockIdx.x < 4096){
    int i = blockIdx.x*256 + threadIdx.x;
    int sel = i>>18;
    const float* src = sel==0?wq: sel==1?wk: sel==2?wv:wo;
    float4 v = ((const float4*)src)[i & 262143];
    ushort4 o; o.x=f2bf(v.x); o.y=f2bf(v.y); o.z=f2bf(v.z); o.w=f2bf(v.w);
    ((ushort4*)out)[i] = o;
  } else {
    int i = (blockIdx.x-4096)*256 + threadIdx.x;  // 131072
    int t = i>>6, j = i&63;
    float inv = powf(10000.0f, -(float)(2*j)*(1.0f/128.0f));
    float a = (float)t * inv;
    cosT[i] = cosf(a);
    sinT[i] = sinf(a);
  }
}

// ---------------- qp/kp from ROPED Q (prescaled) and ROPED KF ----------------
__global__ void qpkp_k(const u16* __restrict__ Qb, const u16* __restrict__ KF,
                       const float* __restrict__ dirs, float* __restrict__ qp, float* __restrict__ kp){
  const float INV_SL2 = 1.0f/SL2C;
  int idx = blockIdx.x*256 + threadIdx.x;   // (b*H+h)*T + t
  int b = idx>>14, rem = idx & 16383;
  int h = rem>>11, t = rem & 2047;
  int bh = b*HH + h;
  float d0 = dirs[h*3], d1 = dirs[h*3+1], d2 = dirs[h*3+2];
  size_t qbase = ((size_t)(b*TT + t))*CC + h*DD;
  qp[idx] = (bf2f(Qb[qbase])*d0 + bf2f(Qb[qbase+1])*d1 + bf2f(Qb[qbase+2])*d2) * INV_SL2;
  // KF frag: d in {0,1,2} -> (d>>4)=0, (d>>3)&1=0, (d&7)=d  => base + t31*8 + d
  size_t kb = ((size_t)(bh*64 + (t>>5))*8)*512 + (size_t)(t&31)*8;
  kp[idx] = bf2f(KF[kb])*d0 + bf2f(KF[kb+1])*d1 + bf2f(KF[kb+2])*d2;
}

// ---------------- GEMM ----------------
// MODE 0: Q: rope + SL2 prescale -> row-major Qb. MODE 5: K: rope -> fragment-packed KF.
// MODE 4: V -> fragment-packed VF. MODE 2: f32 out + residual.
template<int MODE>
__global__ __launch_bounds__(256) void gemm_k(const u16* __restrict__ A, const u16* __restrict__ W,
                                              u16* __restrict__ outb, float* __restrict__ outf,
                                              const float* __restrict__ resid,
                                              const float* __restrict__ cosT, const float* __restrict__ sinT){
  __shared__ __align__(16) u16 sbuf[16384];   // main loop: As=sbuf[0:8192), Bs=[8192:16384); epilogue: 128x128 stage
  u16* As = sbuf;
  u16* Bs = sbuf + 8192;
  const int K = CC;
  int m0 = blockIdx.x*128, n0 = blockIdx.y*128;
  int tid = threadIdx.x, w = tid>>6, l = tid&63;
  int li = l&15, lg = l>>4;
  int wm = w>>1, wn = w&1;
  f32x4 acc[4][4] = {};
  for(int k0=0; k0<K; k0+=64){
    #pragma unroll
    for(int i=0;i<4;i++){
      int L = (w*4+i)*1024 + l*16;
      int row = L>>7;
      int colb = (L&127) ^ ((row&7)<<4);
      gload16(A + ((size_t)(m0+row)*K + k0 + (colb>>1)), (char*)As + (w*4+i)*1024);
      gload16(W + ((size_t)(n0+row)*K + k0 + (colb>>1)), (char*)Bs + (w*4+i)*1024);
    }
    __syncthreads();
    #pragma unroll
    for(int kc=0;kc<2;kc++){
      bf16x8 af[4], bfr[4];
      #pragma unroll
      for(int mi=0;mi<4;mi++){
        int row = wm*64 + mi*16 + li;
        int colb = (kc*64 + lg*16) ^ ((row&7)<<4);
        af[mi] = *(const bf16x8*)((const char*)As + row*128 + colb);
      }
      #pragma unroll
      for(int ni=0;ni<4;ni++){
        int row = wn*64 + ni*16 + li;
        int colb = (kc*64 + lg*16) ^ ((row&7)<<4);
        bfr[ni] = *(const bf16x8*)((const char*)Bs + row*128 + colb);
      }
      #pragma unroll
      for(int mi=0;mi<4;mi++){
        #pragma unroll
        for(int ni=0;ni<4;ni++)
          acc[mi][ni] = mfma16(af[mi], bfr[ni], acc[mi][ni]);
      }
    }
    __syncthreads();
  }

  if(MODE==0 || MODE==5){
    // ---- fused RoPE epilogue: stage bf16 acc in LDS, exchange (d, d^64), rope, pack out ----
    // (numerically identical to old path: GEMM-out was bf16-rounded before the rope pass)
    #pragma unroll
    for(int mi=0;mi<4;mi++){
      #pragma unroll
      for(int ni=0;ni<4;ni++){
        int c = wn*64 + ni*16 + li;
        #pragma unroll
        for(int r=0;r<4;r++){
          int rr = wm*64 + mi*16 + lg*4 + r;
          sbuf[rr*128 + (c ^ ((rr&15)<<3))] = f2bf(acc[mi][ni][r]);   // XOR swizzle both sides
        }
      }
    }
    __syncthreads();
    int rowl = tid & 127, half = tid >> 7;    // thread -> (row, col-half); 16 x 4-col groups each
    int grow = m0 + rowl;
    int t = grow & (TT-1);
    int swz = (rowl&15)<<3;
    const float* cbase = cosT + t*64;
    const float* sbase = sinT + t*64;
    #pragma unroll
    for(int g=0; g<16; g++){
      int c0 = half*64 + g*4;
      int j0 = c0 & 63;
      float4 cv = *(const float4*)(cbase + j0);
      float4 sv4 = *(const float4*)(sbase + j0);
      ushort4 se4 = *(const ushort4*)&sbuf[rowl*128 + (c0 ^ swz)];
      ushort4 pa4 = *(const ushort4*)&sbuf[rowl*128 + ((c0^64) ^ swz)];
      float se[4] = {bf2f(se4.x),bf2f(se4.y),bf2f(se4.z),bf2f(se4.w)};
      float pa[4] = {bf2f(pa4.x),bf2f(pa4.y),bf2f(pa4.z),bf2f(pa4.w)};
      float cc4[4] = {cv.x,cv.y,cv.z,cv.w};
      float ss4[4] = {sv4.x,sv4.y,sv4.z,sv4.w};
      ushort4 o; u16* op = (u16*)&o;
      #pragma unroll
      for(int e=0;e<4;e++){
        float v = half ? (se[e]*cc4[e] + pa[e]*ss4[e]) : (se[e]*cc4[e] - pa[e]*ss4[e]);
        if(MODE==0) v *= SL2C;
        op[e] = f2bf(v);
      }
      if(MODE==0){
        *(ushort4*)(outb + (size_t)grow*CC + n0 + c0) = o;
      } else {
        int b = grow>>11;
        int h = n0>>7;                       // one head per 128-col tile
        int bh = b*HH + h;
        int d0 = c0;
        size_t of = (((size_t)(bh*64 + (t>>5))*8) + (d0>>4))*512 + (((d0>>3)&1)*32 + (t&31))*8 + (d0&7);
        *(ushort4*)(outb + of) = o;
      }
    }
    return;
  }

  #pragma unroll
  for(int mi=0;mi<4;mi++){
    #pragma unroll
    for(int ni=0;ni<4;ni++){
      if(MODE==4){
        int row0 = m0 + wm*64 + mi*16 + lg*4;
        int col = n0 + wn*64 + ni*16 + li;
        int t = row0 & 2047, b = row0>>11;
        int h = col>>7, d = col&127;
        int bh = b*HH + h;
        size_t o = (((size_t)(bh*64 + (t>>5))*8) + (d>>5)*2 + ((t>>4)&1))*512
                   + (((t>>3)&1)*32 + (d&31))*8 + (t&7);
        ushort4 pk;
        pk.x = f2bf(acc[mi][ni][0]); pk.y = f2bf(acc[mi][ni][1]);
        pk.z = f2bf(acc[mi][ni][2]); pk.w = f2bf(acc[mi][ni][3]);
        *(ushort4*)(outb + o) = pk;
      } else {
        #pragma unroll
        for(int r=0;r<4;r++){
          int row = m0 + wm*64 + mi*16 + lg*4 + r;
          int col = n0 + wn*64 + ni*16 + li;
          size_t o = (size_t)row*CC + col;
          outf[o] = acc[mi][ni][r] + resid[o];
        }
      }
    }
  }
}

// ---------------- attention segment state + inner loop (R11/R13-proven body, Q pre-scaled) ----------------
struct SegState { float m1, l1, m2, l2; f32x16 a1[4]; f32x16 a2[4]; };

__device__ __forceinline__ void run_seg(int t, int klo, int khi, int bh, int b, int h,
                                        int l5, int q31,
                                        const u16* __restrict__ Q, const u16* __restrict__ KF,
                                        const u16* __restrict__ VF, const float* __restrict__ qp,
                                        const float* __restrict__ kp, SegState& S){
  const f32x16 zf = {};
  S.m1 = -__builtin_inff(); S.l1 = 0.f; S.m2 = -__builtin_inff(); S.l2 = 0.f;
  #pragma unroll
  for(int dt=0;dt<4;dt++){ S.a1[dt] = zf; S.a2[dt] = zf; }
  if(khi <= klo) return;

  int q0 = t*32, q = q0 + q31;
  bf16x8 qf[8];
  {
    const u16* qbase = Q + ((size_t)(b*TT + q)*CC + h*DD);
    #pragma unroll
    for(int db=0;db<8;db++) qf[db] = *(const bf16x8*)(qbase + db*16 + l5*8);
  }
  const float L2E = 1.442695040888963f;
  bf16x8 qpf;
  {
    float qs = qp[(size_t)bh*TT + q] * L2E;
    u16 qh = f2bf(qs); float qhf = bf2f(qh);
    u16 ql = f2bf(qs - qhf);
    FRAG fq; fq.u[0] = l5? 0u : ((u32)qh | ((u32)qh<<16));
    fq.u[1] = l5? 0u : (u32)ql; fq.u[2]=0; fq.u[3]=0;
    qpf = fq.v;
  }
  const u16* kfp = KF + (size_t)bh*64*4096 + (size_t)klo*4096 + (size_t)(q31 + 32*l5)*8;
  const u16* vfp = VF + (size_t)bh*64*4096 + (size_t)klo*4096 + (size_t)(q31 + 32*l5)*8;
  const float* kpp = kp + (size_t)bh*TT + q31;

  for(int is=klo; is<khi; ++is){
    int ksub = is*32;

    bf16x8 kf0 = *(const bf16x8*)(kfp + 0*512);
    bf16x8 kf1 = *(const bf16x8*)(kfp + 1*512);
    bf16x8 kf2 = *(const bf16x8*)(kfp + 2*512);
    bf16x8 kf3 = *(const bf16x8*)(kfp + 3*512);
    bf16x8 kf4 = *(const bf16x8*)(kfp + 4*512);
    bf16x8 kf5 = *(const bf16x8*)(kfp + 5*512);
    bf16x8 kf6 = *(const bf16x8*)(kfp + 6*512);
    bf16x8 kf7 = *(const bf16x8*)(kfp + 7*512);

    f32x16 s0 = {}, s1a = {};
    __builtin_amdgcn_s_setprio(1);
    s0  = mfma32(kf0, qf[0], s0);  s1a = mfma32(kf1, qf[1], s1a);
    s0  = mfma32(kf2, qf[2], s0);  s1a = mfma32(kf3, qf[3], s1a);
    s0  = mfma32(kf4, qf[4], s0);  s1a = mfma32(kf5, qf[5], s1a);
    s0  = mfma32(kf6, qf[6], s0);  s1a = mfma32(kf7, qf[7], s1a);
    __builtin_amdgcn_s_setprio(0);

    f32x16 gg;
    {
      const f32x16 zf2 = {};
      float kpv = kpp[ksub];
      u16 kh = f2bf(kpv); float khf = bf2f(kh);
      u16 kl = f2bf(kpv - khf);
      FRAG fk; fk.u[0] = l5? 0u : ((u32)kh | ((u32)kl<<16));
      fk.u[1] = l5? 0u : (u32)kh; fk.u[2]=0; fk.u[3]=0;
      gg = mfma32(fk.v, qpf, zf2);
    }

    float sv[16], gv[16];
    #pragma unroll
    for(int rr=0;rr<16;rr++){ sv[rr] = s0[rr]+s1a[rr]; gv[rr] = gg[rr]; }   // Q pre-scaled: log2 domain
    if(ksub + 31 > q0){                       // wave-uniform diagonal test
      #pragma unroll
      for(int rr=0;rr<16;rr++){
        int kg = ksub + (rr&3) + 8*(rr>>2) + 4*l5;
        if(kg > q){ sv[rr] = -__builtin_inff(); gv[rr] = -__builtin_inff(); }
      }
    }

    float mx=-__builtin_inff(), gx=-__builtin_inff();
    #pragma unroll
    for(int rr=0;rr<16;rr++){ mx = fmaxf(mx, sv[rr]); gx = fmaxf(gx, gv[rr]); }
    mx = fmaxf(mx, __shfl_xor(mx,32));
    gx = fmaxf(gx, __shfl_xor(gx,32));
    if(__ballot((mx > S.m1+8.f) | (gx > S.m2+8.f))){
      float mn1 = fmaxf(S.m1,mx), mn2 = fmaxf(S.m2,gx);
      float c1 = exp2f(S.m1-mn1), c2 = exp2f(S.m2-mn2);
      S.l1 *= c1; S.l2 *= c2; S.m1 = mn1; S.m2 = mn2;
      #pragma unroll
      for(int dt=0;dt<4;dt++){ S.a1[dt] *= c1; S.a2[dt] *= c2; }
    }
    float rs1=0.f, rs2=0.f;
    float e1[16], e2[16];
    #pragma unroll
    for(int rr=0;rr<16;rr++){
      e1[rr] = exp2f(sv[rr] - S.m1); rs1 += e1[rr];
      e2[rr] = exp2f(gv[rr] - S.m2); rs2 += e2[rr];
    }
    rs1 += __shfl_xor(rs1,32); rs2 += __shfl_xor(rs2,32);
    S.l1 += rs1; S.l2 += rs2;

    u32 P1[8], P2[8];
    #pragma unroll
    for(int m=0;m<8;m++){ P1[m] = cvtpk(e1[2*m], e1[2*m+1]); P2[m] = cvtpk(e2[2*m], e2[2*m+1]); }
    pl32swap(P1[0],P1[2]); pl32swap(P1[1],P1[3]); pl32swap(P1[4],P1[6]); pl32swap(P1[5],P1[7]);
    pl32swap(P2[0],P2[2]); pl32swap(P2[1],P2[3]); pl32swap(P2[4],P2[6]); pl32swap(P2[5],P2[7]);

    #pragma unroll
    for(int kb2=0;kb2<2;kb2++){
      FRAG f1, f2;
      #pragma unroll
      for(int j2=0;j2<4;j2++){ f1.u[j2] = P1[kb2*4+j2]; f2.u[j2] = P2[kb2*4+j2]; }
      bf16x8 pb1 = f1.v, pb2 = f2.v;
      bf16x8 vf0 = *(const bf16x8*)(vfp + (0+kb2)*512);
      bf16x8 vf1 = *(const bf16x8*)(vfp + (2+kb2)*512);
      bf16x8 vf2 = *(const bf16x8*)(vfp + (4+kb2)*512);
      bf16x8 vf3 = *(const bf16x8*)(vfp + (6+kb2)*512);
      __builtin_amdgcn_s_setprio(1);
      S.a1[0] = mfma32(vf0, pb1, S.a1[0]);  S.a2[0] = mfma32(vf0, pb2, S.a2[0]);
      S.a1[1] = mfma32(vf1, pb1, S.a1[1]);  S.a2[1] = mfma32(vf1, pb2, S.a2[1]);
      S.a1[2] = mfma32(vf2, pb1, S.a1[2]);  S.a2[2] = mfma32(vf2, pb2, S.a2[2]);
      S.a1[3] = mfma32(vf3, pb1, S.a1[3]);  S.a2[3] = mfma32(vf3, pb2, S.a2[3]);
      __builtin_amdgcn_s_setprio(0);
    }
    kfp += 4096; vfp += 4096;
  }
}

// ---------------- fused dual flash attention: pair-balanced waves + in-block LDS merge (R9/R13-proven) ----------------
// NOTE: keep __launch_bounds__(128,2) — combined VGPR+AGPR/wave ~256 (unified file): 3/EU spills (R6/R7);
// prefetch machinery bloats VGPR to 208 and halves occupancy (R12). Splitting the dual softmax into two
// kernels un-shares the V loads + epilogue and regresses (R15). Do not touch.
__global__ __launch_bounds__(128,2) void attn_k(const u16* __restrict__ Q, const u16* __restrict__ KF,
                                                const u16* __restrict__ VF, const float* __restrict__ qp,
                                                const float* __restrict__ kp, const float* __restrict__ hs,
                                                u16* __restrict__ outp){
  __shared__ __align__(16) float lp1[4*64*16];   // wave0's partial a1 [dt][lane][r]
  __shared__ __align__(16) float lp2[4*64*16];   // partial a2
  __shared__ float lml[32*4];                    // per q31: m1,l1,m2,l2
  int bid = blockIdx.x;
  int xcd = bid&7, r = bid>>3;          // r: 0..127
  int bh = xcd*4 + (r&3);               // 4 bh groups per XCD
  int p = r>>2;                         // 0..31 pair index
  int b = bh>>3, h = bh&7;
  int tid = threadIdx.x, w = tid>>6, l = tid&63;
  int l5 = l>>5, q31 = l&31;
  float sh = hs[h];

  SegState S;
  if(w==0){
    // seg0: tile p, full range, direct write
    run_seg(p, 0, p+1, bh, b, h, l5, q31, Q, KF, VF, qp, kp, S);
    {
      float rl1 = 1.0f/S.l1, rl2 = 1.0f/S.l2;
      int q = p*32 + q31;
      u16* obase = outp + (size_t)(b*TT + q)*CC + h*DD;
      #pragma unroll
      for(int dt=0;dt<4;dt++){
        #pragma unroll
        for(int m=0;m<8;m++){
          float oa1 = S.a1[dt][2*m]*rl1,   oa2 = S.a2[dt][2*m]*rl2;
          float ob1 = S.a1[dt][2*m+1]*rl1, ob2 = S.a2[dt][2*m+1]*rl2;
          float oa = oa1 + sh*(oa2-oa1);
          float ob = ob1 + sh*(ob2-ob1);
          int d = dt*32 + (2*m&3) + 8*(m>>1) + 4*l5;
          *(u32*)(obase + d) = cvtpk(oa, ob);
        }
      }
    }
    // seg1: tile 63-p, first half k[0, 31-p) -> partial to LDS
    run_seg(63-p, 0, 31-p, bh, b, h, l5, q31, Q, KF, VF, qp, kp, S);
    #pragma unroll
    for(int dt=0;dt<4;dt++){
      *(f32x16*)&lp1[(dt*64 + l)*16] = S.a1[dt];
      *(f32x16*)&lp2[(dt*64 + l)*16] = S.a2[dt];
    }
    if(l5==0){
      lml[q31*4+0] = S.m1; lml[q31*4+1] = S.l1;
      lml[q31*4+2] = S.m2; lml[q31*4+3] = S.l2;
    }
    __syncthreads();
  } else {
    // wave1: tile 63-p, second half k[31-p, 64-p)
    run_seg(63-p, 31-p, 64-p, bh, b, h, l5, q31, Q, KF, VF, qp, kp, S);
    __syncthreads();
    float mA1 = lml[q31*4+0], lA1 = lml[q31*4+1];
    float mA2 = lml[q31*4+2], lA2 = lml[q31*4+3];
    float M1 = fmaxf(mA1, S.m1), M2 = fmaxf(mA2, S.m2);
    float wA1 = exp2f(mA1-M1), wB1 = exp2f(S.m1-M1);
    float wA2 = exp2f(mA2-M2), wB2 = exp2f(S.m2-M2);
    float r1 = 1.0f/(wA1*lA1 + wB1*S.l1);
    float r2 = 1.0f/(wA2*lA2 + wB2*S.l2);
    int q = (63-p)*32 + q31;
    u16* obase = outp + (size_t)(b*TT + q)*CC + h*DD;
    #pragma unroll
    for(int dt=0;dt<4;dt++){
      f32x16 pa1 = *(const f32x16*)&lp1[(dt*64 + l)*16];
      f32x16 pa2 = *(const f32x16*)&lp2[(dt*64 + l)*16];
      #pragma unroll
      for(int m=0;m<8;m++){
        float oa1 = (wA1*pa1[2*m]   + wB1*S.a1[dt][2*m])*r1;
        float ob1 = (wA1*pa1[2*m+1] + wB1*S.a1[dt][2*m+1])*r1;
        float oa2 = (wA2*pa2[2*m]   + wB2*S.a2[dt][2*m])*r2;
        float ob2 = (wA2*pa2[2*m+1] + wB2*S.a2[dt][2*m+1])*r2;
        float oa = oa1 + sh*(oa2-oa1);
        float ob = ob1 + sh*(ob2-ob1);
        int d = dt*32 + (2*m&3) + 8*(m>>1) + 4*l5;
        *(u32*)(obase + d) = cvtpk(oa, ob);
      }
    }
  }
}

extern "C" void kernel_launch(void* const* d_in, const int* in_sizes, int n_in,
                              void* d_out, int out_size, void* d_ws, size_t ws_size,
                              hipStream_t stream){
  (void)in_sizes; (void)n_in; (void)out_size; (void)ws_size;
  const float* x   = (const float*)d_in[0];
  const float* Wq  = (const float*)d_in[1];
  const float* Wk  = (const float*)d_in[2];
  const float* Wv  = (const float*)d_in[3];
  const float* Wo  = (const float*)d_in[4];
  const float* lng = (const float*)d_in[5];
  const float* lnb = (const float*)d_in[6];
  const float* hsc = (const float*)d_in[7];
  const float* hdr = (const float*)d_in[8];

  char* ws = (char*)d_ws;
  const size_t MB = 1048576;
  u16* xn   = (u16*)ws;                 // 16MB (LN out, later attn out)
  u16* wbf  = (u16*)(ws + 16*MB);       // 8MB bf16 weights Wq|Wk|Wv|Wo
  u16* Qb   = (u16*)(ws + 24*MB);       // 16MB roped+prescaled Q
  u16* VF   = (u16*)(ws + 56*MB);       // 16MB packed V fragments
  u16* KF   = (u16*)(ws + 72*MB);       // 16MB packed roped K fragments
  float* cosT = (float*)(ws + 88*MB);
  float* sinT = cosT + 131072;
  float* qp   = sinT + 131072;
  float* kp   = qp + 65536;

  ln_k<<<8192,256,0,stream>>>(x, lng, lnb, xn);
  prep_k<<<4608,256,0,stream>>>(Wq,Wk,Wv,Wo,wbf,cosT,sinT);
  gemm_k<0><<<dim3(64,8),256,0,stream>>>(xn, wbf,          Qb, nullptr, nullptr, cosT, sinT);  // Q + rope + prescale
  gemm_k<5><<<dim3(64,8),256,0,stream>>>(xn, wbf+1048576,  KF, nullptr, nullptr, cosT, sinT);  // K + rope -> KF
  gemm_k<4><<<dim3(64,8),256,0,stream>>>(xn, wbf+2097152,  VF, nullptr, nullptr, nullptr, nullptr);
  qpkp_k<<<256,256,0,stream>>>(Qb,KF,hdr,qp,kp);
  attn_k<<<1024,128,0,stream>>>(Qb,KF,VF,qp,kp,hsc,xn);
  gemm_k<2><<<dim3(64,8),256,0,stream>>>(xn, wbf+3145728, nullptr, (float*)d_out, x, nullptr, nullptr);
}